// Round 1
// baseline (416.864 us; speedup 1.0000x reference)
//
#include <hip/hip_runtime.h>
#include <hip/hip_bf16.h>

#define B_ 2
#define S_ 2048
#define HID_ 2048
#define NH_ 16
#define HD_ 128
#define NKV_ 4
#define M_ (B_*S_)          // 4096
#define NQKV_ 3072          // 2048 Q + 512 K + 512 V
#define QSCALE 0.08838834764831845f  // 1/sqrt(128)

typedef __bf16 bf16x8 __attribute__((ext_vector_type(8)));
typedef float f32x4 __attribute__((ext_vector_type(4)));

typedef __attribute__((address_space(1))) const unsigned int gas_uint;
typedef __attribute__((address_space(3))) unsigned int las_uint;

__device__ __forceinline__ unsigned short f2bfu(float x) {
  __hip_bfloat16 h = __float2bfloat16(x);
  return __builtin_bit_cast(unsigned short, h);
}

__device__ __forceinline__ void gload_lds16(const void* g, void* l) {
  __builtin_amdgcn_global_load_lds((gas_uint*)g, (las_uint*)l, 16, 0, 0);
}

// ---------------- prep kernels ----------------

__global__ void k_cvt(const float* __restrict__ src, unsigned short* __restrict__ dst, int n4) {
  int i = blockIdx.x * 256 + threadIdx.x;
  if (i >= n4) return;
  float4 v = ((const float4*)src)[i];
  ushort4 o;
  o.x = f2bfu(v.x); o.y = f2bfu(v.y); o.z = f2bfu(v.z); o.w = f2bfu(v.w);
  ((ushort4*)dst)[i] = o;
}

// dst[C][R] = bf16(src[R][C])  -- 32x32 LDS tile transpose
__global__ void k_tcvt(const float* __restrict__ src, unsigned short* __restrict__ dst, int R, int C) {
  __shared__ float t[32][33];
  int bc = blockIdx.x * 32, br = blockIdx.y * 32;
  int tx = threadIdx.x & 31, ty = threadIdx.x >> 5;
  for (int i = ty; i < 32; i += 8)
    t[i][tx] = src[(size_t)(br + i) * C + bc + tx];
  __syncthreads();
  for (int i = ty; i < 32; i += 8)
    dst[(size_t)(bc + i) * R + br + tx] = f2bfu(t[tx][i]);
}

__global__ void k_bias(const float* __restrict__ bq, const float* __restrict__ bk,
                       const float* __restrict__ bv, float* __restrict__ out) {
  int i = blockIdx.x * 256 + threadIdx.x;  // 3072
  float v = (i < 2048) ? bq[i] : (i < 2560 ? bk[i - 2048] : bv[i - 2560]);
  out[i] = v;
}

__global__ void k_ropetab(float* __restrict__ cosT, float* __restrict__ sinT) {
  int idx = blockIdx.x * 256 + threadIdx.x;  // S*64
  int s = idx >> 6, i = idx & 63;
  float invf = expf(-(float)i * (9.210340371976184f / 64.f));  // 10000^(-i/64)
  float ang = (float)s * invf;
  cosT[idx] = cosf(ang);
  sinT[idx] = sinf(ang);
}

// RoPE Q: Cqkv[M][3072] -> Qr[B][NH][S][HD] bf16, pre-scaled by 1/sqrt(HD)
__global__ void k_ropeq(const float* __restrict__ Cq, const float* __restrict__ cosT,
                        const float* __restrict__ sinT, unsigned short* __restrict__ Qr) {
  int idx = blockIdx.x * 256 + threadIdx.x;    // M*NH*64
  int i = idx & 63, h = (idx >> 6) & (NH_ - 1), m = idx >> 10;
  int s = m & (S_ - 1), b = m >> 11;
  const float* row = Cq + (size_t)m * NQKV_ + h * HD_;
  float x1 = row[i], x2 = row[i + 64];
  float c = cosT[(s << 6) + i], sn = sinT[(s << 6) + i];
  size_t base = ((size_t)(b * NH_ + h) * S_ + s) * HD_;
  Qr[base + i]      = f2bfu((x1 * c - x2 * sn) * QSCALE);
  Qr[base + i + 64] = f2bfu((x1 * sn + x2 * c) * QSCALE);
}

// RoPE K: -> Kr[B][NKV][S][HD] bf16 (no scale)
__global__ void k_ropek(const float* __restrict__ Cq, const float* __restrict__ cosT,
                        const float* __restrict__ sinT, unsigned short* __restrict__ Kr) {
  int idx = blockIdx.x * 256 + threadIdx.x;    // M*NKV*64
  int i = idx & 63, kv = (idx >> 6) & (NKV_ - 1), m = idx >> 8;
  int s = m & (S_ - 1), b = m >> 11;
  const float* row = Cq + (size_t)m * NQKV_ + 2048 + kv * HD_;
  float x1 = row[i], x2 = row[i + 64];
  float c = cosT[(s << 6) + i], sn = sinT[(s << 6) + i];
  size_t base = ((size_t)(b * NKV_ + kv) * S_ + s) * HD_;
  Kr[base + i]      = f2bfu(x1 * c - x2 * sn);
  Kr[base + i + 64] = f2bfu(x1 * sn + x2 * c);
}

// V: Cqkv[...][2560+kv*128+d] -> Vt[B][NKV][HD][S] bf16 (transposed via LDS)
__global__ void k_vt(const float* __restrict__ Cq, unsigned short* __restrict__ Vt) {
  __shared__ float t[32][129];
  int bx = blockIdx.x;                 // B*NKV*(S/32) = 512
  int st = bx & 63, kv = (bx >> 6) & 3, b = bx >> 8;
  int s0 = st * 32;
  int tid = threadIdx.x;
  for (int j = 0; j < 16; ++j) {
    int idx = j * 256 + tid;           // 4096 = 32*128
    int si = idx >> 7, d = idx & 127;
    t[si][d] = Cq[(size_t)(b * S_ + s0 + si) * NQKV_ + 2560 + kv * HD_ + d];
  }
  __syncthreads();
  for (int j = 0; j < 16; ++j) {
    int idx = j * 256 + tid;
    int d = idx >> 5, si = idx & 31;
    Vt[((size_t)(b * NKV_ + kv) * HD_ + d) * S_ + s0 + si] = f2bfu(t[si][d]);
  }
}

// ---------------- GEMM: C[M][N] = A[M][K] @ Bt[N][K]^T + bias ----------------
// m97 structure: 128x128 tile, BK=64, global_load_lds w=16, XOR-swizzled LDS (T2, rule #21)

__global__ __launch_bounds__(256, 2)
void k_gemm(const unsigned short* __restrict__ A, const unsigned short* __restrict__ Bt,
            const float* __restrict__ bias, float* __restrict__ C,
            int Md, int Nd, int Kd) {
  __shared__ __align__(16) unsigned short As[128 * 64];
  __shared__ __align__(16) unsigned short Bs[128 * 64];
  int nt = Nd >> 7;
  int nwg = (Md >> 7) * nt;
  int bid = blockIdx.x;
  int wg = bid;
  if ((nwg & 7) == 0) { int cpx = nwg >> 3; wg = (bid & 7) * cpx + (bid >> 3); }
  int bm = wg / nt, bn = wg - bm * nt;
  int tid = threadIdx.x;
  int lane = tid & 63, w = tid >> 6;
  int wm = (w >> 1) << 6, wn = (w & 1) << 6;
  int lr = lane & 15, lg = lane >> 4;
  f32x4 acc[4][4] = {};

  const int chunkbase = w << 2;
  const int boff = lane << 4;
  const int nK = Kd >> 6;
  const size_t rowstride = (size_t)Kd * 2;  // bytes per row

  for (int kt = 0; kt < nK; ++kt) {
#pragma unroll
    for (int i = 0; i < 4; ++i) {
      int off = ((chunkbase + i) << 10) + boff;  // linear byte offset in 16KB tile
      int row = off >> 7;
      int colb = off & 127;
      int scolb = colb ^ ((row & 7) << 4);       // pre-swizzled global source (rule #21)
      const char* ga = (const char*)A + (size_t)(bm * 128 + row) * rowstride + (kt << 7) + scolb;
      const char* gb = (const char*)Bt + (size_t)(bn * 128 + row) * rowstride + (kt << 7) + scolb;
      gload_lds16(ga, (char*)As + ((chunkbase + i) << 10));
      gload_lds16(gb, (char*)Bs + ((chunkbase + i) << 10));
    }
    __syncthreads();
#pragma unroll
    for (int kk = 0; kk < 2; ++kk) {
      bf16x8 a[4], b[4];
      int kb = ((kk << 5) + (lg << 3)) << 1;
#pragma unroll
      for (int mi = 0; mi < 4; ++mi) {
        int row = wm + (mi << 4) + lr;
        a[mi] = *(const bf16x8*)((const char*)As + (row << 7) + (kb ^ ((row & 7) << 4)));
      }
#pragma unroll
      for (int ni = 0; ni < 4; ++ni) {
        int row = wn + (ni << 4) + lr;
        b[ni] = *(const bf16x8*)((const char*)Bs + (row << 7) + (kb ^ ((row & 7) << 4)));
      }
#pragma unroll
      for (int mi = 0; mi < 4; ++mi)
#pragma unroll
        for (int ni = 0; ni < 4; ++ni)
          acc[mi][ni] = __builtin_amdgcn_mfma_f32_16x16x32_bf16(a[mi], b[ni], acc[mi][ni], 0, 0, 0);
    }
    __syncthreads();
  }
  // C/D layout: col = lane&15, row = (lane>>4)*4 + reg (m89-verified)
#pragma unroll
  for (int mi = 0; mi < 4; ++mi) {
    int r0 = bm * 128 + wm + (mi << 4) + (lg << 2);
#pragma unroll
    for (int ni = 0; ni < 4; ++ni) {
      int col = bn * 128 + wn + (ni << 4) + lr;
      float bz = bias[col];
#pragma unroll
      for (int r = 0; r < 4; ++r)
        C[(size_t)(r0 + r) * Nd + col] = acc[mi][ni][r] + bz;
    }
  }
}

// ---------------- flash attention ----------------
// block = 4 waves; wave owns 16 q-rows; KV tile = 32; K staged in swizzled LDS;
// V^T read direct from global (L2-resident); online softmax in f32.

__global__ __launch_bounds__(256, 2)
void k_attn(const unsigned short* __restrict__ Qr, const unsigned short* __restrict__ Kr,
            const unsigned short* __restrict__ Vt, unsigned short* __restrict__ Ob) {
  __shared__ __align__(16) unsigned short Ks[32 * 128];
  __shared__ __align__(16) unsigned short Ps[4][16 * 32];
  int bid = blockIdx.x;
  int bx = (bid & 7) * 128 + (bid >> 3);  // XCD swizzle: one (b,kv-group) per XCD chunk
  int qt = bx & 31, h = (bx >> 5) & 15, b = bx >> 9;
  int kvh = h >> 2;
  int tid = threadIdx.x, lane = tid & 63, w = tid >> 6;
  int lr = lane & 15, lg = lane >> 4;
  int q0 = (qt << 6) + (w << 4);

  const unsigned short* Qp = Qr + (((size_t)(b * NH_ + h) * S_ + q0) << 7);
  const unsigned short* Kp = Kr + (((size_t)(b * NKV_ + kvh) * S_) << 7);
  const unsigned short* Vp = Vt + (((size_t)(b * NKV_ + kvh) * HD_) << 11);

  bf16x8 qa[4];
#pragma unroll
  for (int dc = 0; dc < 4; ++dc)
    qa[dc] = *(const bf16x8*)(Qp + ((size_t)lr << 7) + (dc << 5) + (lg << 3));

  f32x4 acc_o[8] = {};
  float m_r[4] = {-1e30f, -1e30f, -1e30f, -1e30f};
  float l_r[4] = {0.f, 0.f, 0.f, 0.f};

  int ntile = (qt + 1) << 1;              // block-level trip count (uniform)
  int wntile = ((q0 + 15) >> 5) + 1;      // this wave's causal trip count

  for (int t0i = 0; t0i < ntile; ++t0i) {
    int t0 = t0i << 5;
    // stage K tile [32][128] bf16 (8KB), rows 256B, swizzle slot ^= row&15
#pragma unroll
    for (int i = 0; i < 2; ++i) {
      int chunk = (w << 1) + i;
      int off = (chunk << 10) + (lane << 4);
      int row = off >> 8;
      int colb = off & 255;
      int scolb = colb ^ ((row & 15) << 4);
      gload_lds16((const char*)Kp + (size_t)(t0 + row) * 256 + scolb,
                  (char*)Ks + (chunk << 10));
    }
    __syncthreads();
    if (t0i < wntile) {
      f32x4 sc[2] = {};
#pragma unroll
      for (int tt = 0; tt < 2; ++tt) {
        int row = (tt << 4) + lr;
        int sw = (row & 15) << 4;
#pragma unroll
        for (int dc = 0; dc < 4; ++dc) {
          int kb = ((dc << 5) + (lg << 3)) << 1;
          bf16x8 kf = *(const bf16x8*)((const char*)Ks + (row << 8) + (kb ^ sw));
          sc[tt] = __builtin_amdgcn_mfma_f32_16x16x32_bf16(qa[dc], kf, sc[tt], 0, 0, 0);
        }
      }
      if (t0 + 31 > q0) {  // diagonal tile(s): causal mask; every row keeps >=1 valid col
#pragma unroll
        for (int tt = 0; tt < 2; ++tt)
#pragma unroll
          for (int r = 0; r < 4; ++r)
            if (t0 + (tt << 4) + lr > q0 + (lg << 2) + r) sc[tt][r] = -1e30f;
      }
#pragma unroll
      for (int r = 0; r < 4; ++r) {
        float mx = fmaxf(sc[0][r], sc[1][r]);
#pragma unroll
        for (int off = 1; off < 16; off <<= 1)
          mx = fmaxf(mx, __shfl_xor(mx, off));
        float mn = fmaxf(m_r[r], mx);
        float al = __expf(m_r[r] - mn);
        float p0 = __expf(sc[0][r] - mn);
        float p1 = __expf(sc[1][r] - mn);
        m_r[r] = mn;
        float ps = p0 + p1;
#pragma unroll
        for (int off = 1; off < 16; off <<= 1)
          ps += __shfl_xor(ps, off);
        l_r[r] = l_r[r] * al + ps;
#pragma unroll
        for (int dt = 0; dt < 8; ++dt) acc_o[dt][r] *= al;
        int prow = (lg << 2) + r;
        Ps[w][(prow << 5) + lr]      = f2bfu(p0);
        Ps[w][(prow << 5) + 16 + lr] = f2bfu(p1);
      }
      bf16x8 pa = *(const bf16x8*)(&Ps[w][(lr << 5) + (lg << 3)]);
#pragma unroll
      for (int dt = 0; dt < 8; ++dt) {
        bf16x8 vf = *(const bf16x8*)(Vp + ((size_t)((dt << 4) + lr) << 11) + t0 + (lg << 3));
        acc_o[dt] = __builtin_amdgcn_mfma_f32_16x16x32_bf16(pa, vf, acc_o[dt], 0, 0, 0);
      }
    }
    __syncthreads();
  }
  float inv_l[4];
#pragma unroll
  for (int r = 0; r < 4; ++r) inv_l[r] = 1.f / l_r[r];
  size_t obase = ((size_t)(b * S_) + q0) * (NH_ * HD_) + h * HD_;
#pragma unroll
  for (int dt = 0; dt < 8; ++dt)
#pragma unroll
    for (int r = 0; r < 4; ++r)
      Ob[obase + (size_t)((lg << 2) + r) * (NH_ * HD_) + (dt << 4) + lr] =
          f2bfu(acc_o[dt][r] * inv_l[r]);
}

// ---------------- launch ----------------

extern "C" void kernel_launch(void* const* d_in, const int* in_sizes, int n_in,
                              void* d_out, int out_size, void* d_ws, size_t ws_size,
                              hipStream_t stream) {
  const float* X  = (const float*)d_in[0];
  // d_in[1] = causal mask (structure known; ignored)
  const float* Wq = (const float*)d_in[2];
  const float* bq = (const float*)d_in[3];
  const float* Wk = (const float*)d_in[4];
  const float* bk = (const float*)d_in[5];
  const float* Wv = (const float*)d_in[6];
  const float* bv = (const float*)d_in[7];
  const float* Wo = (const float*)d_in[8];
  const float* bo = (const float*)d_in[9];
  float* out = (float*)d_out;

  char* ws = (char*)d_ws;
  unsigned short* Xb  = (unsigned short*)(ws);                  // 16,777,216 B
  unsigned short* Wt  = (unsigned short*)(ws + 16777216);       // 12,582,912
  unsigned short* Wot = (unsigned short*)(ws + 29360128);       //  8,388,608
  float* Bqkv         = (float*)(ws + 37748736);                //     12,288
  float* cosT         = (float*)(ws + 37761024);                //    524,288
  float* sinT         = (float*)(ws + 38285312);                //    524,288
  float* Cqkv         = (float*)(ws + 38809600);                // 50,331,648
  unsigned short* Qr  = (unsigned short*)(ws + 89141248);       // 16,777,216
  unsigned short* Kr  = (unsigned short*)(ws + 105918464);      //  4,194,304
  unsigned short* Vtb = (unsigned short*)(ws + 110112768);      //  4,194,304
  unsigned short* Ob  = (unsigned short*)(ws + 114307072);      // 16,777,216
  // total ~131 MB

  k_cvt<<<(M_ * HID_ / 4 + 255) / 256, 256, 0, stream>>>(X, Xb, M_ * HID_ / 4);
  k_tcvt<<<dim3(2048 / 32, 2048 / 32), 256, 0, stream>>>(Wq, Wt, 2048, 2048);
  k_tcvt<<<dim3(512 / 32, 2048 / 32), 256, 0, stream>>>(Wk, Wt + 2048 * 2048, 2048, 512);
  k_tcvt<<<dim3(512 / 32, 2048 / 32), 256, 0, stream>>>(Wv, Wt + 2560 * 2048, 2048, 512);
  k_tcvt<<<dim3(2048 / 32, 2048 / 32), 256, 0, stream>>>(Wo, Wot, 2048, 2048);
  k_bias<<<12, 256, 0, stream>>>(bq, bk, bv, Bqkv);
  k_ropetab<<<S_ * 64 / 256, 256, 0, stream>>>(cosT, sinT);

  k_gemm<<<(M_ / 128) * (NQKV_ / 128), 256, 0, stream>>>(Xb, Wt, Bqkv, Cqkv, M_, NQKV_, HID_);

  k_ropeq<<<M_ * NH_ * 64 / 256, 256, 0, stream>>>(Cqkv, cosT, sinT, Qr);
  k_ropek<<<M_ * NKV_ * 64 / 256, 256, 0, stream>>>(Cqkv, cosT, sinT, Kr);
  k_vt<<<B_ * NKV_ * (S_ / 32), 256, 0, stream>>>(Cqkv, Vtb);

  k_attn<<<B_ * NH_ * (S_ / 64), 256, 0, stream>>>(Qr, Kr, Vtb, Ob);

  k_gemm<<<(M_ / 128) * (HID_ / 128), 256, 0, stream>>>(Ob, Wot, bo, out, M_, HID_, NH_ * HD_);
}

// Round 2
// 360.687 us; speedup vs baseline: 1.1557x; 1.1557x over previous
//
#include <hip/hip_runtime.h>
#include <hip/hip_bf16.h>

#define B_ 2
#define S_ 2048
#define HID_ 2048
#define NH_ 16
#define HD_ 128
#define NKV_ 4
#define M_ (B_*S_)          // 4096
#define NQKV_ 3072          // 2048 Q + 512 K + 512 V
#define QSCALE 0.08838834764831845f  // 1/sqrt(128)

typedef __bf16 bf16x8 __attribute__((ext_vector_type(8)));
typedef float f32x4 __attribute__((ext_vector_type(4)));

typedef __attribute__((address_space(1))) const unsigned int gas_uint;
typedef __attribute__((address_space(3))) unsigned int las_uint;

__device__ __forceinline__ unsigned short f2bfu(float x) {
  __hip_bfloat16 h = __float2bfloat16(x);
  return __builtin_bit_cast(unsigned short, h);
}

__device__ __forceinline__ void gload_lds16(const void* g, void* l) {
  __builtin_amdgcn_global_load_lds((gas_uint*)g, (las_uint*)l, 16, 0, 0);
}

// ---------------- prep kernels ----------------

__global__ void k_cvt(const float* __restrict__ src, unsigned short* __restrict__ dst, int n4) {
  int i = blockIdx.x * 256 + threadIdx.x;
  if (i >= n4) return;
  float4 v = ((const float4*)src)[i];
  ushort4 o;
  o.x = f2bfu(v.x); o.y = f2bfu(v.y); o.z = f2bfu(v.z); o.w = f2bfu(v.w);
  ((ushort4*)dst)[i] = o;
}

// dst[C][R] = bf16(src[R][C])  -- 32x32 LDS tile transpose
__global__ void k_tcvt(const float* __restrict__ src, unsigned short* __restrict__ dst, int R, int C) {
  __shared__ float t[32][33];
  int bc = blockIdx.x * 32, br = blockIdx.y * 32;
  int tx = threadIdx.x & 31, ty = threadIdx.x >> 5;
  for (int i = ty; i < 32; i += 8)
    t[i][tx] = src[(size_t)(br + i) * C + bc + tx];
  __syncthreads();
  for (int i = ty; i < 32; i += 8)
    dst[(size_t)(bc + i) * R + br + tx] = f2bfu(t[tx][i]);
}

__global__ void k_bias(const float* __restrict__ bq, const float* __restrict__ bk,
                       const float* __restrict__ bv, float* __restrict__ out) {
  int i = blockIdx.x * 256 + threadIdx.x;  // 3072
  float v = (i < 2048) ? bq[i] : (i < 2560 ? bk[i - 2048] : bv[i - 2560]);
  out[i] = v;
}

__global__ void k_ropetab(float* __restrict__ cosT, float* __restrict__ sinT) {
  int idx = blockIdx.x * 256 + threadIdx.x;  // S*64
  int s = idx >> 6, i = idx & 63;
  float invf = expf(-(float)i * (9.210340371976184f / 64.f));  // 10000^(-i/64)
  float ang = (float)s * invf;
  cosT[idx] = cosf(ang);
  sinT[idx] = sinf(ang);
}

// RoPE Q: Cqkv[M][3072] -> Qr[B][NH][S][HD] bf16, pre-scaled by 1/sqrt(HD)
__global__ void k_ropeq(const float* __restrict__ Cq, const float* __restrict__ cosT,
                        const float* __restrict__ sinT, unsigned short* __restrict__ Qr) {
  int idx = blockIdx.x * 256 + threadIdx.x;    // M*NH*64
  int i = idx & 63, h = (idx >> 6) & (NH_ - 1), m = idx >> 10;
  int s = m & (S_ - 1), b = m >> 11;
  const float* row = Cq + (size_t)m * NQKV_ + h * HD_;
  float x1 = row[i], x2 = row[i + 64];
  float c = cosT[(s << 6) + i], sn = sinT[(s << 6) + i];
  size_t base = ((size_t)(b * NH_ + h) * S_ + s) * HD_;
  Qr[base + i]      = f2bfu((x1 * c - x2 * sn) * QSCALE);
  Qr[base + i + 64] = f2bfu((x1 * sn + x2 * c) * QSCALE);
}

// RoPE K: -> Kr[B][NKV][S][HD] bf16 (no scale)
__global__ void k_ropek(const float* __restrict__ Cq, const float* __restrict__ cosT,
                        const float* __restrict__ sinT, unsigned short* __restrict__ Kr) {
  int idx = blockIdx.x * 256 + threadIdx.x;    // M*NKV*64
  int i = idx & 63, kv = (idx >> 6) & (NKV_ - 1), m = idx >> 8;
  int s = m & (S_ - 1), b = m >> 11;
  const float* row = Cq + (size_t)m * NQKV_ + 2048 + kv * HD_;
  float x1 = row[i], x2 = row[i + 64];
  float c = cosT[(s << 6) + i], sn = sinT[(s << 6) + i];
  size_t base = ((size_t)(b * NKV_ + kv) * S_ + s) * HD_;
  Kr[base + i]      = f2bfu(x1 * c - x2 * sn);
  Kr[base + i + 64] = f2bfu(x1 * sn + x2 * c);
}

// V: Cqkv[...][2560+kv*128+d] -> Vt[B][NKV][HD][S] bf16 (transposed via LDS)
__global__ void k_vt(const float* __restrict__ Cq, unsigned short* __restrict__ Vt) {
  __shared__ float t[32][129];
  int bx = blockIdx.x;                 // B*NKV*(S/32) = 512
  int st = bx & 63, kv = (bx >> 6) & 3, b = bx >> 8;
  int s0 = st * 32;
  int tid = threadIdx.x;
  for (int j = 0; j < 16; ++j) {
    int idx = j * 256 + tid;           // 4096 = 32*128
    int si = idx >> 7, d = idx & 127;
    t[si][d] = Cq[(size_t)(b * S_ + s0 + si) * NQKV_ + 2560 + kv * HD_ + d];
  }
  __syncthreads();
  for (int j = 0; j < 16; ++j) {
    int idx = j * 256 + tid;
    int d = idx >> 5, si = idx & 31;
    Vt[((size_t)(b * NKV_ + kv) * HD_ + d) * S_ + s0 + si] = f2bfu(t[si][d]);
  }
}

// ---------------- GEMM: C[M][N] = A[M][K] @ Bt[N][K]^T + bias ----------------
// m97 structure: 128x128 tile, BK=64, global_load_lds w=16, XOR-swizzled LDS (T2, rule #21)

__global__ __launch_bounds__(256, 2)
void k_gemm(const unsigned short* __restrict__ A, const unsigned short* __restrict__ Bt,
            const float* __restrict__ bias, float* __restrict__ C,
            int Md, int Nd, int Kd) {
  __shared__ __align__(16) unsigned short As[128 * 64];
  __shared__ __align__(16) unsigned short Bs[128 * 64];
  int nt = Nd >> 7;
  int nwg = (Md >> 7) * nt;
  int bid = blockIdx.x;
  int wg = bid;
  if ((nwg & 7) == 0) { int cpx = nwg >> 3; wg = (bid & 7) * cpx + (bid >> 3); }
  int bm = wg / nt, bn = wg - bm * nt;
  int tid = threadIdx.x;
  int lane = tid & 63, w = tid >> 6;
  int wm = (w >> 1) << 6, wn = (w & 1) << 6;
  int lr = lane & 15, lg = lane >> 4;
  f32x4 acc[4][4] = {};

  const int chunkbase = w << 2;
  const int boff = lane << 4;
  const int nK = Kd >> 6;
  const size_t rowstride = (size_t)Kd * 2;  // bytes per row

  for (int kt = 0; kt < nK; ++kt) {
#pragma unroll
    for (int i = 0; i < 4; ++i) {
      int off = ((chunkbase + i) << 10) + boff;  // linear byte offset in 16KB tile
      int row = off >> 7;
      int colb = off & 127;
      int scolb = colb ^ ((row & 7) << 4);       // pre-swizzled global source (rule #21)
      const char* ga = (const char*)A + (size_t)(bm * 128 + row) * rowstride + (kt << 7) + scolb;
      const char* gb = (const char*)Bt + (size_t)(bn * 128 + row) * rowstride + (kt << 7) + scolb;
      gload_lds16(ga, (char*)As + ((chunkbase + i) << 10));
      gload_lds16(gb, (char*)Bs + ((chunkbase + i) << 10));
    }
    __syncthreads();
#pragma unroll
    for (int kk = 0; kk < 2; ++kk) {
      bf16x8 a[4], b[4];
      int kb = ((kk << 5) + (lg << 3)) << 1;
#pragma unroll
      for (int mi = 0; mi < 4; ++mi) {
        int row = wm + (mi << 4) + lr;
        a[mi] = *(const bf16x8*)((const char*)As + (row << 7) + (kb ^ ((row & 7) << 4)));
      }
#pragma unroll
      for (int ni = 0; ni < 4; ++ni) {
        int row = wn + (ni << 4) + lr;
        b[ni] = *(const bf16x8*)((const char*)Bs + (row << 7) + (kb ^ ((row & 7) << 4)));
      }
#pragma unroll
      for (int mi = 0; mi < 4; ++mi)
#pragma unroll
        for (int ni = 0; ni < 4; ++ni)
          acc[mi][ni] = __builtin_amdgcn_mfma_f32_16x16x32_bf16(a[mi], b[ni], acc[mi][ni], 0, 0, 0);
    }
    __syncthreads();
  }
  // C/D layout: col = lane&15, row = (lane>>4)*4 + reg (m89-verified)
#pragma unroll
  for (int mi = 0; mi < 4; ++mi) {
    int r0 = bm * 128 + wm + (mi << 4) + (lg << 2);
#pragma unroll
    for (int ni = 0; ni < 4; ++ni) {
      int col = bn * 128 + wn + (ni << 4) + lr;
      float bz = bias[col];
#pragma unroll
      for (int r = 0; r < 4; ++r)
        C[(size_t)(r0 + r) * Nd + col] = acc[mi][ni][r] + bz;
    }
  }
}

// ---------------- flash attention v2 ----------------
// 4 waves/block, wave = 16 q-rows; KVBLK=64; double-buffered swizzled K in LDS;
// one barrier per KV tile; uniform trip count (qt+1) across waves;
// Ps padded to 72-ushort stride (conflict-free-ish); V^T direct from global.

__global__ __launch_bounds__(256, 2)
void k_attn(const unsigned short* __restrict__ Qr, const unsigned short* __restrict__ Kr,
            const unsigned short* __restrict__ Vt, unsigned short* __restrict__ Ob) {
  __shared__ __align__(16) unsigned short Ks[2][64 * 128];
  __shared__ __align__(16) unsigned short Ps[4][16 * 72];
  int bid = blockIdx.x;
  int bx = (bid & 7) * 128 + (bid >> 3);  // XCD swizzle (1024 % 8 == 0, bijective)
  int qt = 31 - (bx & 31);                // long blocks first
  int h = (bx >> 5) & 15, b = bx >> 9;
  int kvh = h >> 2;
  int tid = threadIdx.x, lane = tid & 63, w = tid >> 6;
  int lr = lane & 15, lg = lane >> 4;
  int q0 = (qt << 6) + (w << 4);

  const unsigned short* Qp = Qr + (((size_t)(b * NH_ + h) * S_ + q0) << 7);
  const unsigned short* Kp = Kr + (((size_t)(b * NKV_ + kvh) * S_) << 7);
  const unsigned short* Vp = Vt + (((size_t)(b * NKV_ + kvh) * HD_) << 11);

  bf16x8 qa[4];
#pragma unroll
  for (int dc = 0; dc < 4; ++dc)
    qa[dc] = *(const bf16x8*)(Qp + ((size_t)lr << 7) + (dc << 5) + (lg << 3));

  f32x4 acc_o[8] = {};
  float m_r[4] = {-1e30f, -1e30f, -1e30f, -1e30f};
  float l_r[4] = {0.f, 0.f, 0.f, 0.f};

  const int ntile = qt + 1;   // uniform across all 4 waves (q-tile 64 = KVBLK)

  // stage K tile t into buffer bsel: 64 rows x 256B, XOR-swizzled source (rule #21)
#define STAGE_K(bsel, t)                                                        \
  {                                                                             \
    const char* kbase = (const char*)Kp + ((size_t)(t) << 14);                  \
    _Pragma("unroll")                                                           \
    for (int i_ = 0; i_ < 4; ++i_) {                                            \
      int woff_ = (i_ << 12) + (w << 10);                                       \
      int off_ = woff_ + (lane << 4);                                           \
      int row_ = off_ >> 8;                                                     \
      int colb_ = off_ & 255;                                                   \
      int scolb_ = colb_ ^ ((row_ & 15) << 4);                                  \
      gload_lds16(kbase + ((size_t)row_ << 8) + scolb_,                         \
                  (char*)Ks[bsel] + woff_);                                     \
    }                                                                           \
  }

  STAGE_K(0, 0);
  __syncthreads();

  for (int t = 0; t < ntile; ++t) {
    int t0 = t << 6;
    if (t + 1 < ntile) STAGE_K((t + 1) & 1, t + 1);   // overlaps with compute below
    const char* Kb = (const char*)Ks[t & 1];

    // QK^T: sc[tt][r] = score(q-row q0+lg*4+r, col t0+tt*16+lr)
    f32x4 sc[4] = {};
#pragma unroll
    for (int tt = 0; tt < 4; ++tt) {
      int row = (tt << 4) + lr;
      int sw = (row & 15) << 4;
#pragma unroll
      for (int dc = 0; dc < 4; ++dc) {
        int kb = (dc << 6) + (lg << 4);
        bf16x8 kf = *(const bf16x8*)(Kb + (row << 8) + (kb ^ sw));
        sc[tt] = __builtin_amdgcn_mfma_f32_16x16x32_bf16(qa[dc], kf, sc[tt], 0, 0, 0);
      }
    }
    if (t == ntile - 1) {  // diagonal tile: causal mask (every row keeps col 0 valid)
#pragma unroll
      for (int tt = 0; tt < 4; ++tt)
#pragma unroll
        for (int r = 0; r < 4; ++r)
          if (t0 + (tt << 4) + lr > q0 + (lg << 2) + r) sc[tt][r] = -1e30f;
    }
    // online softmax (16-lane tree over lr within each lg group)
#pragma unroll
    for (int r = 0; r < 4; ++r) {
      float mx = fmaxf(fmaxf(sc[0][r], sc[1][r]), fmaxf(sc[2][r], sc[3][r]));
#pragma unroll
      for (int off = 1; off < 16; off <<= 1)
        mx = fmaxf(mx, __shfl_xor(mx, off));
      float mn = fmaxf(m_r[r], mx);
      float al = __expf(m_r[r] - mn);
      float p0 = __expf(sc[0][r] - mn);
      float p1 = __expf(sc[1][r] - mn);
      float p2 = __expf(sc[2][r] - mn);
      float p3 = __expf(sc[3][r] - mn);
      m_r[r] = mn;
      float ps = p0 + p1 + p2 + p3;
#pragma unroll
      for (int off = 1; off < 16; off <<= 1)
        ps += __shfl_xor(ps, off);
      l_r[r] = l_r[r] * al + ps;
#pragma unroll
      for (int dt = 0; dt < 8; ++dt) acc_o[dt][r] *= al;
      int prow = (lg << 2) + r;
      Ps[w][prow * 72 + lr]      = f2bfu(p0);
      Ps[w][prow * 72 + 16 + lr] = f2bfu(p1);
      Ps[w][prow * 72 + 32 + lr] = f2bfu(p2);
      Ps[w][prow * 72 + 48 + lr] = f2bfu(p3);
    }
    // PV: acc_o[dt] += P[16x64] @ V^T rows (d = dt*16+lr), ks = 32-wide K chunks
    bf16x8 pa[2];
    pa[0] = *(const bf16x8*)(&Ps[w][lr * 72 + (lg << 3)]);
    pa[1] = *(const bf16x8*)(&Ps[w][lr * 72 + 32 + (lg << 3)]);
#pragma unroll
    for (int ks = 0; ks < 2; ++ks)
#pragma unroll
      for (int dt = 0; dt < 8; ++dt) {
        bf16x8 vf = *(const bf16x8*)(Vp + ((size_t)((dt << 4) + lr) << 11) + t0 + (ks << 5) + (lg << 3));
        acc_o[dt] = __builtin_amdgcn_mfma_f32_16x16x32_bf16(pa[ks], vf, acc_o[dt], 0, 0, 0);
      }
    __syncthreads();  // drains next-tile stage (vmcnt) + all waves done with Ks[t&1]
  }

  float inv_l[4];
#pragma unroll
  for (int r = 0; r < 4; ++r) inv_l[r] = 1.f / l_r[r];
  size_t obase = ((size_t)(b * S_) + q0) * (NH_ * HD_) + h * HD_;
#pragma unroll
  for (int dt = 0; dt < 8; ++dt)
#pragma unroll
    for (int r = 0; r < 4; ++r)
      Ob[obase + (size_t)((lg << 2) + r) * (NH_ * HD_) + (dt << 4) + lr] =
          f2bfu(acc_o[dt][r] * inv_l[r]);
}

// ---------------- launch ----------------

extern "C" void kernel_launch(void* const* d_in, const int* in_sizes, int n_in,
                              void* d_out, int out_size, void* d_ws, size_t ws_size,
                              hipStream_t stream) {
  const float* X  = (const float*)d_in[0];
  // d_in[1] = causal mask (structure known; ignored)
  const float* Wq = (const float*)d_in[2];
  const float* bq = (const float*)d_in[3];
  const float* Wk = (const float*)d_in[4];
  const float* bk = (const float*)d_in[5];
  const float* Wv = (const float*)d_in[6];
  const float* bv = (const float*)d_in[7];
  const float* Wo = (const float*)d_in[8];
  const float* bo = (const float*)d_in[9];
  float* out = (float*)d_out;

  char* ws = (char*)d_ws;
  unsigned short* Xb  = (unsigned short*)(ws);                  // 16,777,216 B
  unsigned short* Wt  = (unsigned short*)(ws + 16777216);       // 12,582,912
  unsigned short* Wot = (unsigned short*)(ws + 29360128);       //  8,388,608
  float* Bqkv         = (float*)(ws + 37748736);                //     12,288
  float* cosT         = (float*)(ws + 37761024);                //    524,288
  float* sinT         = (float*)(ws + 38285312);                //    524,288
  float* Cqkv         = (float*)(ws + 38809600);                // 50,331,648
  unsigned short* Qr  = (unsigned short*)(ws + 89141248);       // 16,777,216
  unsigned short* Kr  = (unsigned short*)(ws + 105918464);      //  4,194,304
  unsigned short* Vtb = (unsigned short*)(ws + 110112768);      //  4,194,304
  unsigned short* Ob  = (unsigned short*)(ws + 114307072);      // 16,777,216
  // total ~131 MB

  k_cvt<<<(M_ * HID_ / 4 + 255) / 256, 256, 0, stream>>>(X, Xb, M_ * HID_ / 4);
  k_tcvt<<<dim3(2048 / 32, 2048 / 32), 256, 0, stream>>>(Wq, Wt, 2048, 2048);
  k_tcvt<<<dim3(512 / 32, 2048 / 32), 256, 0, stream>>>(Wk, Wt + 2048 * 2048, 2048, 512);
  k_tcvt<<<dim3(512 / 32, 2048 / 32), 256, 0, stream>>>(Wv, Wt + 2560 * 2048, 2048, 512);
  k_tcvt<<<dim3(2048 / 32, 2048 / 32), 256, 0, stream>>>(Wo, Wot, 2048, 2048);
  k_bias<<<12, 256, 0, stream>>>(bq, bk, bv, Bqkv);
  k_ropetab<<<S_ * 64 / 256, 256, 0, stream>>>(cosT, sinT);

  k_gemm<<<(M_ / 128) * (NQKV_ / 128), 256, 0, stream>>>(Xb, Wt, Bqkv, Cqkv, M_, NQKV_, HID_);

  k_ropeq<<<M_ * NH_ * 64 / 256, 256, 0, stream>>>(Cqkv, cosT, sinT, Qr);
  k_ropek<<<M_ * NKV_ * 64 / 256, 256, 0, stream>>>(Cqkv, cosT, sinT, Kr);
  k_vt<<<B_ * NKV_ * (S_ / 32), 256, 0, stream>>>(Cqkv, Vtb);

  k_attn<<<B_ * NH_ * (S_ / 64), 256, 0, stream>>>(Qr, Kr, Vtb, Ob);

  k_gemm<<<(M_ / 128) * (HID_ / 128), 256, 0, stream>>>(Ob, Wot, bo, out, M_, HID_, NH_ * HD_);
}

// Round 4
// 277.551 us; speedup vs baseline: 1.5019x; 1.2995x over previous
//
#include <hip/hip_runtime.h>
#include <hip/hip_bf16.h>

#define B_ 2
#define S_ 2048
#define HID_ 2048
#define NH_ 16
#define HD_ 128
#define NKV_ 4
#define M_ (B_*S_)          // 4096
#define NQKV_ 3072          // 2048 Q + 512 K + 512 V
#define QSCALE 0.08838834764831845f  // 1/sqrt(128)

typedef __bf16 bf16x8 __attribute__((ext_vector_type(8)));
typedef float f32x4 __attribute__((ext_vector_type(4)));
typedef float f32x16 __attribute__((ext_vector_type(16)));

typedef __attribute__((address_space(1))) const unsigned int gas_uint;
typedef __attribute__((address_space(3))) unsigned int las_uint;

__device__ __forceinline__ unsigned short f2bfu(float x) {
  __hip_bfloat16 h = __float2bfloat16(x);
  return __builtin_bit_cast(unsigned short, h);
}

__device__ __forceinline__ unsigned int pack2bf(float lo, float hi) {
  return (unsigned int)f2bfu(lo) | ((unsigned int)f2bfu(hi) << 16);
}

__device__ __forceinline__ void gload_lds16(const void* g, void* l) {
  __builtin_amdgcn_global_load_lds((gas_uint*)g, (las_uint*)l, 16, 0, 0);
}

// ---------------- prep kernels ----------------

__global__ void k_cvt(const float* __restrict__ src, unsigned short* __restrict__ dst, int n4) {
  int i = blockIdx.x * 256 + threadIdx.x;
  if (i >= n4) return;
  float4 v = ((const float4*)src)[i];
  ushort4 o;
  o.x = f2bfu(v.x); o.y = f2bfu(v.y); o.z = f2bfu(v.z); o.w = f2bfu(v.w);
  ((ushort4*)dst)[i] = o;
}

// dst[C][R] = bf16(src[R][C])  -- 32x32 LDS tile transpose
__global__ void k_tcvt(const float* __restrict__ src, unsigned short* __restrict__ dst, int R, int C) {
  __shared__ float t[32][33];
  int bc = blockIdx.x * 32, br = blockIdx.y * 32;
  int tx = threadIdx.x & 31, ty = threadIdx.x >> 5;
  for (int i = ty; i < 32; i += 8)
    t[i][tx] = src[(size_t)(br + i) * C + bc + tx];
  __syncthreads();
  for (int i = ty; i < 32; i += 8)
    dst[(size_t)(bc + i) * R + br + tx] = f2bfu(t[tx][i]);
}

__global__ void k_bias(const float* __restrict__ bq, const float* __restrict__ bk,
                       const float* __restrict__ bv, float* __restrict__ out) {
  int i = blockIdx.x * 256 + threadIdx.x;  // 3072
  float v = (i < 2048) ? bq[i] : (i < 2560 ? bk[i - 2048] : bv[i - 2560]);
  out[i] = v;
}

__global__ void k_ropetab(float* __restrict__ cosT, float* __restrict__ sinT) {
  int idx = blockIdx.x * 256 + threadIdx.x;  // S*64
  int s = idx >> 6, i = idx & 63;
  float invf = expf(-(float)i * (9.210340371976184f / 64.f));  // 10000^(-i/64)
  float ang = (float)s * invf;
  cosT[idx] = cosf(ang);
  sinT[idx] = sinf(ang);
}

// RoPE Q: Cqkv[M][3072] -> Qr[B][NH][S][HD] bf16, pre-scaled by 1/sqrt(HD)
__global__ void k_ropeq(const float* __restrict__ Cq, const float* __restrict__ cosT,
                        const float* __restrict__ sinT, unsigned short* __restrict__ Qr) {
  int idx = blockIdx.x * 256 + threadIdx.x;    // M*NH*64
  int i = idx & 63, h = (idx >> 6) & (NH_ - 1), m = idx >> 10;
  int s = m & (S_ - 1), b = m >> 11;
  const float* row = Cq + (size_t)m * NQKV_ + h * HD_;
  float x1 = row[i], x2 = row[i + 64];
  float c = cosT[(s << 6) + i], sn = sinT[(s << 6) + i];
  size_t base = ((size_t)(b * NH_ + h) * S_ + s) * HD_;
  Qr[base + i]      = f2bfu((x1 * c - x2 * sn) * QSCALE);
  Qr[base + i + 64] = f2bfu((x1 * sn + x2 * c) * QSCALE);
}

// RoPE K: -> Kr[B][NKV][S][HD] bf16 (no scale)
__global__ void k_ropek(const float* __restrict__ Cq, const float* __restrict__ cosT,
                        const float* __restrict__ sinT, unsigned short* __restrict__ Kr) {
  int idx = blockIdx.x * 256 + threadIdx.x;    // M*NKV*64
  int i = idx & 63, kv = (idx >> 6) & (NKV_ - 1), m = idx >> 8;
  int s = m & (S_ - 1), b = m >> 11;
  const float* row = Cq + (size_t)m * NQKV_ + 2048 + kv * HD_;
  float x1 = row[i], x2 = row[i + 64];
  float c = cosT[(s << 6) + i], sn = sinT[(s << 6) + i];
  size_t base = ((size_t)(b * NKV_ + kv) * S_ + s) * HD_;
  Kr[base + i]      = f2bfu(x1 * c - x2 * sn);
  Kr[base + i + 64] = f2bfu(x1 * sn + x2 * c);
}

// V: Cqkv[...][2560+kv*128+d] -> Vt[B][NKV][HD][S] bf16 (transposed via LDS)
__global__ void k_vt(const float* __restrict__ Cq, unsigned short* __restrict__ Vt) {
  __shared__ float t[32][129];
  int bx = blockIdx.x;                 // B*NKV*(S/32) = 512
  int st = bx & 63, kv = (bx >> 6) & 3, b = bx >> 8;
  int s0 = st * 32;
  int tid = threadIdx.x;
  for (int j = 0; j < 16; ++j) {
    int idx = j * 256 + tid;           // 4096 = 32*128
    int si = idx >> 7, d = idx & 127;
    t[si][d] = Cq[(size_t)(b * S_ + s0 + si) * NQKV_ + 2560 + kv * HD_ + d];
  }
  __syncthreads();
  for (int j = 0; j < 16; ++j) {
    int idx = j * 256 + tid;
    int d = idx >> 5, si = idx & 31;
    Vt[((size_t)(b * NKV_ + kv) * HD_ + d) * S_ + s0 + si] = f2bfu(t[si][d]);
  }
}

// ---------------- GEMM: C[M][N] = A[M][K] @ Bt[N][K]^T + bias ----------------
// m97 structure: 128x128 tile, BK=64, global_load_lds w=16, XOR-swizzled LDS (T2, rule #21)

__global__ __launch_bounds__(256, 2)
void k_gemm(const unsigned short* __restrict__ A, const unsigned short* __restrict__ Bt,
            const float* __restrict__ bias, float* __restrict__ C,
            int Md, int Nd, int Kd) {
  __shared__ __align__(16) unsigned short As[128 * 64];
  __shared__ __align__(16) unsigned short Bs[128 * 64];
  int nt = Nd >> 7;
  int nwg = (Md >> 7) * nt;
  int bid = blockIdx.x;
  int wg = bid;
  if ((nwg & 7) == 0) { int cpx = nwg >> 3; wg = (bid & 7) * cpx + (bid >> 3); }
  int bm = wg / nt, bn = wg - bm * nt;
  int tid = threadIdx.x;
  int lane = tid & 63, w = tid >> 6;
  int wm = (w >> 1) << 6, wn = (w & 1) << 6;
  int lr = lane & 15, lg = lane >> 4;
  f32x4 acc[4][4] = {};

  const int chunkbase = w << 2;
  const int boff = lane << 4;
  const int nK = Kd >> 6;
  const size_t rowstride = (size_t)Kd * 2;  // bytes per row

  for (int kt = 0; kt < nK; ++kt) {
#pragma unroll
    for (int i = 0; i < 4; ++i) {
      int off = ((chunkbase + i) << 10) + boff;  // linear byte offset in 16KB tile
      int row = off >> 7;
      int colb = off & 127;
      int scolb = colb ^ ((row & 7) << 4);       // pre-swizzled global source (rule #21)
      const char* ga = (const char*)A + (size_t)(bm * 128 + row) * rowstride + (kt << 7) + scolb;
      const char* gb = (const char*)Bt + (size_t)(bn * 128 + row) * rowstride + (kt << 7) + scolb;
      gload_lds16(ga, (char*)As + ((chunkbase + i) << 10));
      gload_lds16(gb, (char*)Bs + ((chunkbase + i) << 10));
    }
    __syncthreads();
#pragma unroll
    for (int kk = 0; kk < 2; ++kk) {
      bf16x8 a[4], b[4];
      int kb = ((kk << 5) + (lg << 3)) << 1;
#pragma unroll
      for (int mi = 0; mi < 4; ++mi) {
        int row = wm + (mi << 4) + lr;
        a[mi] = *(const bf16x8*)((const char*)As + (row << 7) + (kb ^ ((row & 7) << 4)));
      }
#pragma unroll
      for (int ni = 0; ni < 4; ++ni) {
        int row = wn + (ni << 4) + lr;
        b[ni] = *(const bf16x8*)((const char*)Bs + (row << 7) + (kb ^ ((row & 7) << 4)));
      }
#pragma unroll
      for (int mi = 0; mi < 4; ++mi)
#pragma unroll
        for (int ni = 0; ni < 4; ++ni)
          acc[mi][ni] = __builtin_amdgcn_mfma_f32_16x16x32_bf16(a[mi], b[ni], acc[mi][ni], 0, 0, 0);
    }
    __syncthreads();
  }
  // C/D layout: col = lane&15, row = (lane>>4)*4 + reg (m89-verified)
#pragma unroll
  for (int mi = 0; mi < 4; ++mi) {
    int r0 = bm * 128 + wm + (mi << 4) + (lg << 2);
#pragma unroll
    for (int ni = 0; ni < 4; ++ni) {
      int col = bn * 128 + wn + (ni << 4) + lr;
      float bz = bias[col];
#pragma unroll
      for (int r = 0; r < 4; ++r)
        C[(size_t)(r0 + r) * Nd + col] = acc[mi][ni][r] + bz;
    }
  }
}

// ---------------- flash attention v3b: swapped-operand 32x32, shfl_xor exchanges ----------------
// 4 warps x 32 q-rows = 128 q/block; KVBLK=64 (2 subs of 32), double-buffered swizzled K LDS.
// QK^T = mfma(K, Q^T) -> S^T: lane holds 16 scores of q-row (lane&31); partner lane^32 the rest.
// Softmax lane-local; all cross-lane exchange via __shfl_xor(.,32) (unambiguous semantics).
// PV = mfma(V^T, P^T) -> O^T accumulated so rescale is per-lane. Defer-max THR=8 (T13).

__global__ __launch_bounds__(256, 2)
void k_attn(const unsigned short* __restrict__ Qr, const unsigned short* __restrict__ Kr,
            const unsigned short* __restrict__ Vt, unsigned short* __restrict__ Ob) {
  __shared__ __align__(16) unsigned short Ks[2][64 * 128];
  int bid = blockIdx.x;
  int bx = (bid & 7) * 64 + (bid >> 3);   // 512 blocks, bijective XCD swizzle
  int qt = 15 - (bx & 15);                // long blocks first
  int h = (bx >> 4) & 15, b = bx >> 8;
  int kvh = h >> 2;
  int tid = threadIdx.x, lane = tid & 63, w = tid >> 6;
  int ql = lane & 31, hi = lane >> 5;
  int q0 = (qt << 7) + (w << 5);          // warp's first q row
  int qrow = q0 + ql;                     // this lane's q row (softmax + O^T are for this row)

  const unsigned short* Qp = Qr + (((size_t)(b * NH_ + h) * S_) << 7);
  const unsigned short* Kp = Kr + (((size_t)(b * NKV_ + kvh) * S_) << 7);
  const unsigned short* Vp = Vt + (((size_t)(b * NKV_ + kvh) * HD_) << 11);

  // Q fragments: qa[c] = Q[qrow][c*16 + hi*8 .. +8]  (B-operand of swapped QK^T)
  bf16x8 qa[8];
#pragma unroll
  for (int c = 0; c < 8; ++c)
    qa[c] = *(const bf16x8*)(Qp + (((size_t)qrow) << 7) + (c << 4) + (hi << 3));

  f32x16 acc[4] = {};                     // acc[dc][r] = O^T[d = dc*32 + crow(r,hi)][qrow]
  float m_r = -1e30f, l_r = 0.f;

  const int ntile = (qt + 1) << 1;        // KV64 tiles, uniform across warps

#define STAGE_K(bsel, t)                                                        \
  {                                                                             \
    const char* kbase = (const char*)Kp + ((size_t)(t) << 14);                  \
    _Pragma("unroll")                                                           \
    for (int i_ = 0; i_ < 4; ++i_) {                                            \
      int woff_ = (i_ << 12) + (w << 10);                                       \
      int off_ = woff_ + (lane << 4);                                           \
      int row_ = off_ >> 8;                                                     \
      int colb_ = off_ & 255;                                                   \
      int scolb_ = colb_ ^ ((row_ & 15) << 4);                                  \
      gload_lds16(kbase + ((size_t)row_ << 8) + scolb_,                         \
                  (char*)Ks[bsel] + woff_);                                     \
    }                                                                           \
  }

  STAGE_K(0, 0);
  __syncthreads();

  for (int t = 0; t < ntile; ++t) {
    if (t + 1 < ntile) STAGE_K((t + 1) & 1, t + 1);
    const char* Kb = (const char*)Ks[t & 1];

#pragma unroll
    for (int sub = 0; sub < 2; ++sub) {
      int kvbase = (t << 6) + (sub << 5);
      if (kvbase > q0 + 31) continue;     // fully masked for this warp (warp-uniform)

      // QK^T: S^T[kv][q], A = K rows (kv = sub*32 + ql), B = Q^T (from qa)
      f32x16 st = {};
      int krow = (sub << 5) + ql;
      int sw = (krow & 15) << 4;
#pragma unroll
      for (int c = 0; c < 8; ++c) {
        int cb = (c << 5) + (hi << 4);    // byte col within 256B row
        bf16x8 kf = *(const bf16x8*)(Kb + (krow << 8) + (cb ^ sw));
        st = __builtin_amdgcn_mfma_f32_32x32x16_bf16(kf, qa[c], st, 0, 0, 0);
      }
      // causal mask on diagonal sub: kv = kvbase + (r&3) + 8*(r>>2) + 4*hi
      if (kvbase + 31 > q0) {
#pragma unroll
        for (int r = 0; r < 16; ++r) {
          int kv = kvbase + (r & 3) + ((r >> 2) << 3) + (hi << 2);
          if (kv > qrow) st[r] = -1e30f;
        }
      }
      // lane-local online softmax (row = qrow; partner lane^32 has other 16 kv)
      float pmax = st[0];
#pragma unroll
      for (int r = 1; r < 16; ++r) pmax = fmaxf(pmax, st[r]);
      pmax = fmaxf(pmax, __shfl_xor(pmax, 32));
      if (!__all(pmax <= m_r + 8.f)) {    // defer-max (T13)
        float mn = fmaxf(m_r, pmax);
        float al = __expf(m_r - mn);
        m_r = mn;
        l_r *= al;
#pragma unroll
        for (int dc = 0; dc < 4; ++dc) acc[dc] = acc[dc] * al;
      }
      float p[16];
      float ps = 0.f;
#pragma unroll
      for (int r = 0; r < 16; ++r) { p[r] = __expf(st[r] - m_r); ps += p[r]; }
      ps += __shfl_xor(ps, 32);
      l_r += ps;
      // pack P -> bf16 words; redistribute to PV B-operand layout via lane^32 exchange.
      // own kv offsets (hi=0): W0={0,1} W1={2,3} W2={8,9} W3={10,11} W4={16,17} W5={18,19} W6={24,25} W7={26,27}
      //                (hi=1): +4 on each pair.
      unsigned int W[8];
#pragma unroll
      for (int i = 0; i < 8; ++i) W[i] = pack2bf(p[2 * i], p[2 * i + 1]);
      unsigned int pw0 = __shfl_xor(W[0], 32), pw1 = __shfl_xor(W[1], 32);
      unsigned int pw2 = __shfl_xor(W[2], 32), pw3 = __shfl_xor(W[3], 32);
      unsigned int pw4 = __shfl_xor(W[4], 32), pw5 = __shfl_xor(W[5], 32);
      unsigned int pw6 = __shfl_xor(W[6], 32), pw7 = __shfl_xor(W[7], 32);
      uint4 u0, u1;
      u0.x = hi ? pw2 : W[0];   // k=hi*8+{0,1}: hi=0 -> {0,1}; hi=1 -> partner's {8,9}
      u0.y = hi ? pw3 : W[1];   // {2,3} / {10,11}
      u0.z = hi ? W[2] : pw0;   // {4,5} from partner / own {12,13}
      u0.w = hi ? W[3] : pw1;   // {6,7} / {14,15}
      u1.x = hi ? pw6 : W[4];   // {16,17} / {24,25}
      u1.y = hi ? pw7 : W[5];   // {18,19} / {26,27}
      u1.z = hi ? W[6] : pw4;   // {20,21} / {28,29}
      u1.w = hi ? W[7] : pw5;   // {22,23} / {30,31}
      bf16x8 pa0 = __builtin_bit_cast(bf16x8, u0);
      bf16x8 pa1 = __builtin_bit_cast(bf16x8, u1);
      // PV: O^T += V^T · P^T ; A = V^T rows (d = dc*32 + ql), k = kv slot
#pragma unroll
      for (int dc = 0; dc < 4; ++dc) {
        const unsigned short* vrow = Vp + (((size_t)((dc << 5) + ql)) << 11) + kvbase + (hi << 3);
        bf16x8 vf0 = *(const bf16x8*)(vrow);
        bf16x8 vf1 = *(const bf16x8*)(vrow + 16);
        acc[dc] = __builtin_amdgcn_mfma_f32_32x32x16_bf16(vf0, pa0, acc[dc], 0, 0, 0);
        acc[dc] = __builtin_amdgcn_mfma_f32_32x32x16_bf16(vf1, pa1, acc[dc], 0, 0, 0);
      }
    }
    __syncthreads();  // all waves done with Ks[t&1]; drains next-tile stage
  }

  float inv = 1.f / l_r;
  unsigned short* obase = Ob + ((((size_t)(b * S_) + qrow)) << 11) + (h << 7) + (hi << 2);
#pragma unroll
  for (int dc = 0; dc < 4; ++dc)
#pragma unroll
    for (int g = 0; g < 4; ++g) {
      ushort4 o;
      o.x = f2bfu(acc[dc][4 * g + 0] * inv);
      o.y = f2bfu(acc[dc][4 * g + 1] * inv);
      o.z = f2bfu(acc[dc][4 * g + 2] * inv);
      o.w = f2bfu(acc[dc][4 * g + 3] * inv);
      *(ushort4*)(obase + (dc << 5) + (g << 3)) = o;
    }
}

// ---------------- launch ----------------

extern "C" void kernel_launch(void* const* d_in, const int* in_sizes, int n_in,
                              void* d_out, int out_size, void* d_ws, size_t ws_size,
                              hipStream_t stream) {
  const float* X  = (const float*)d_in[0];
  // d_in[1] = causal mask (structure known; ignored)
  const float* Wq = (const float*)d_in[2];
  const float* bq = (const float*)d_in[3];
  const float* Wk = (const float*)d_in[4];
  const float* bk = (const float*)d_in[5];
  const float* Wv = (const float*)d_in[6];
  const float* bv = (const float*)d_in[7];
  const float* Wo = (const float*)d_in[8];
  const float* bo = (const float*)d_in[9];
  float* out = (float*)d_out;

  char* ws = (char*)d_ws;
  unsigned short* Xb  = (unsigned short*)(ws);                  // 16,777,216 B
  unsigned short* Wt  = (unsigned short*)(ws + 16777216);       // 12,582,912
  unsigned short* Wot = (unsigned short*)(ws + 29360128);       //  8,388,608
  float* Bqkv         = (float*)(ws + 37748736);                //     12,288
  float* cosT         = (float*)(ws + 37761024);                //    524,288
  float* sinT         = (float*)(ws + 38285312);                //    524,288
  float* Cqkv         = (float*)(ws + 38809600);                // 50,331,648
  unsigned short* Qr  = (unsigned short*)(ws + 89141248);       // 16,777,216
  unsigned short* Kr  = (unsigned short*)(ws + 105918464);      //  4,194,304
  unsigned short* Vtb = (unsigned short*)(ws + 110112768);      //  4,194,304
  unsigned short* Ob  = (unsigned short*)(ws + 114307072);      // 16,777,216
  // total ~131 MB

  k_cvt<<<(M_ * HID_ / 4 + 255) / 256, 256, 0, stream>>>(X, Xb, M_ * HID_ / 4);
  k_tcvt<<<dim3(2048 / 32, 2048 / 32), 256, 0, stream>>>(Wq, Wt, 2048, 2048);
  k_tcvt<<<dim3(512 / 32, 2048 / 32), 256, 0, stream>>>(Wk, Wt + 2048 * 2048, 2048, 512);
  k_tcvt<<<dim3(512 / 32, 2048 / 32), 256, 0, stream>>>(Wv, Wt + 2560 * 2048, 2048, 512);
  k_tcvt<<<dim3(2048 / 32, 2048 / 32), 256, 0, stream>>>(Wo, Wot, 2048, 2048);
  k_bias<<<12, 256, 0, stream>>>(bq, bk, bv, Bqkv);
  k_ropetab<<<S_ * 64 / 256, 256, 0, stream>>>(cosT, sinT);

  k_gemm<<<(M_ / 128) * (NQKV_ / 128), 256, 0, stream>>>(Xb, Wt, Bqkv, Cqkv, M_, NQKV_, HID_);

  k_ropeq<<<M_ * NH_ * 64 / 256, 256, 0, stream>>>(Cqkv, cosT, sinT, Qr);
  k_ropek<<<M_ * NKV_ * 64 / 256, 256, 0, stream>>>(Cqkv, cosT, sinT, Kr);
  k_vt<<<B_ * NKV_ * (S_ / 32), 256, 0, stream>>>(Cqkv, Vtb);

  k_attn<<<B_ * NH_ * (S_ / 128), 256, 0, stream>>>(Qr, Kr, Vtb, Ob);

  k_gemm<<<(M_ / 128) * (HID_ / 128), 256, 0, stream>>>(Ob, Wot, bo, out, M_, HID_, NH_ * HD_);
}